// Round 5
// baseline (307.490 us; speedup 1.0000x reference)
//
#include <hip/hip_runtime.h>
#include <math.h>

#define HD 128
#define WD 128
#define BB 32
#define KK 32
#define NPIX (BB*HD*WD)   // 524288

typedef _Float16 f16;
typedef __attribute__((ext_vector_type(8))) _Float16 f16x8;
typedef __attribute__((ext_vector_type(4))) float f32x4;

// byte offset of 16B chunk g within 64B row; bijective over (row mod 8) -> all 32 banks
__device__ __forceinline__ int swz(int row, int g){
  return row*64 + (((g + (row >> 1)) & 3) << 4);
}

// ---------------- fused CNN via f16 MFMA ----------------
__global__ __launch_bounds__(512, 2) void cnn_kernel(
    const int* __restrict__ X,
    const float* __restrict__ w1, const float* __restrict__ b1,
    const float* __restrict__ w2, const float* __restrict__ b2,
    const float* __restrict__ w3, const float* __restrict__ b3,
    f16* __restrict__ phi)
{
  __shared__ f16 sW1f[9*11*40];      // [tap][class(11; 10=zero)][40-pad oc], bias folded into tap4
  __shared__ int   sX[20*36];
  __shared__ float sB2[32], sB3[32];
  __shared__ f16 x1[612*32];         // halo 18x34 rows x 32 ic, swizzled; reused as y2
  __shared__ f16 w2t[9*32*32];       // [tap*32+oc][ic], swizzled
  __shared__ f16 w3t[32*32];         // [oe][ic], swizzled

  const int tid = threadIdx.x;
  const int img = blockIdx.z;
  const int bh0 = blockIdx.y * 16;
  const int bw0 = blockIdx.x * 32;

  for (int i = tid; i < 9*11*32; i += 512) {
    int tap = i / 352, c = (i % 352) >> 5, oc = i & 31;
    float v = (c < 10) ? w1[tap*320 + c*32 + oc] : 0.f;
    if (tap == 4 && c < 10) v += b1[oc];
    sW1f[(tap*11 + c)*40 + oc] = (f16)v;
  }
  for (int i = tid; i < 9*32*32; i += 512) {
    int tap = i >> 10, ic = (i >> 5) & 31, oc = i & 31;
    int off = swz(tap*32 + oc, ic >> 3) + (ic & 7)*2;
    *(f16*)((char*)w2t + off) = (f16)w2[i];
  }
  for (int i = tid; i < 32*32; i += 512) {
    int ic = i >> 5, oe = i & 31;
    int off = swz(oe, ic >> 3) + (ic & 7)*2;
    *(f16*)((char*)w3t + off) = (f16)w3[i];
  }
  if (tid < 32) { sB2[tid] = b2[tid]; sB3[tid] = b3[tid]; }
  for (int i = tid; i < 20*36; i += 512) {
    int ti = i / 36, tj = i % 36;
    int gh = bh0 - 2 + ti, gw = bw0 - 2 + tj;
    sX[i] = (gh >= 0 && gh < HD && gw >= 0 && gw < WD) ? X[(img*HD + gh)*WD + gw] : 10;
  }
  __syncthreads();

  // conv1: packed-f16 class-row gather -> relu -> x1 (swizzled)
  for (int p = tid; p < 612; p += 512) {
    int hr = p / 34, hc = p - hr*34;
    int gh = bh0 + hr - 1, gw = bw0 + hc - 1;
    if (gh >= 0 && gh < HD && gw >= 0 && gw < WD) {
      f16x8 acc[4];
      {
        int c = sX[hr*36 + hc];
        const f16* wr = &sW1f[c*40];
        #pragma unroll
        for (int g = 0; g < 4; g++) acc[g] = *(const f16x8*)(wr + g*8);
      }
      #pragma unroll
      for (int tap = 1; tap < 9; tap++) {
        const int ti = tap/3, tj = tap%3;
        int c = sX[(hr+ti)*36 + hc + tj];
        const f16* wr = &sW1f[(tap*11 + c)*40];
        #pragma unroll
        for (int g = 0; g < 4; g++) acc[g] += *(const f16x8*)(wr + g*8);
      }
      #pragma unroll
      for (int g = 0; g < 4; g++) {
        f16x8 r = acc[g];
        #pragma unroll
        for (int j = 0; j < 8; j++) r[j] = (r[j] > (f16)0.f) ? r[j] : (f16)0.f;
        *(f16x8*)((char*)x1 + swz(p, g)) = r;
      }
    } else {
      f16x8 z;
      #pragma unroll
      for (int j = 0; j < 8; j++) z[j] = (f16)0.f;
      #pragma unroll
      for (int g = 0; g < 4; g++) *(f16x8*)((char*)x1 + swz(p, g)) = z;
    }
  }
  __syncthreads();

  // conv2 via MFMA
  const int lane = tid & 63;
  const int wv   = tid >> 6;
  const int lr   = lane & 15;
  const int kg   = lane >> 4;
  const int mts  = wv * 4;

  int arow0[4];
  #pragma unroll
  for (int q = 0; q < 4; q++) {
    int px = (mts + q)*16 + lr;
    arow0[q] = (px >> 5)*34 + (px & 31);
  }
  float b2v0 = sB2[lr], b2v1 = sB2[lr + 16];
  f32x4 acc[4][2];
  #pragma unroll
  for (int q = 0; q < 4; q++) {
    acc[q][0] = (f32x4){b2v0, b2v0, b2v0, b2v0};
    acc[q][1] = (f32x4){b2v1, b2v1, b2v1, b2v1};
  }
  #pragma unroll
  for (int tap = 0; tap < 9; tap++) {
    const int ti = tap/3, tj = tap%3;
    f16x8 bf0 = *(const f16x8*)((const char*)w2t + swz(tap*32 + lr,      kg));
    f16x8 bf1 = *(const f16x8*)((const char*)w2t + swz(tap*32 + lr + 16, kg));
    #pragma unroll
    for (int q = 0; q < 4; q++) {
      int row = arow0[q] + ti*34 + tj;
      f16x8 af = *(const f16x8*)((const char*)x1 + swz(row, kg));
      acc[q][0] = __builtin_amdgcn_mfma_f32_16x16x32_f16(af, bf0, acc[q][0], 0, 0, 0);
      acc[q][1] = __builtin_amdgcn_mfma_f32_16x16x32_f16(af, bf1, acc[q][1], 0, 0, 0);
    }
  }
  __syncthreads();

  // relu -> y2 (reuse x1)
  #pragma unroll
  for (int q = 0; q < 4; q++)
    #pragma unroll
    for (int nt = 0; nt < 2; nt++) {
      int oc = nt*16 + lr;
      #pragma unroll
      for (int rg = 0; rg < 4; rg++) {
        int px = (mts + q)*16 + kg*4 + rg;
        int off = swz(px, oc >> 3) + (oc & 7)*2;
        *(f16*)((char*)x1 + off) = (f16)fmaxf(acc[q][nt][rg], 0.f);
      }
    }
  __syncthreads();

  // conv3 via MFMA + write phi (f16)
  {
    f16x8 cf0 = *(const f16x8*)((const char*)w3t + swz(lr,      kg));
    f16x8 cf1 = *(const f16x8*)((const char*)w3t + swz(lr + 16, kg));
    float b3v0 = sB3[lr], b3v1 = sB3[lr + 16];
    #pragma unroll
    for (int q = 0; q < 4; q++) {
      f16x8 af = *(const f16x8*)((const char*)x1 + swz((mts + q)*16 + lr, kg));
      f32x4 o0 = (f32x4){b3v0, b3v0, b3v0, b3v0};
      f32x4 o1 = (f32x4){b3v1, b3v1, b3v1, b3v1};
      o0 = __builtin_amdgcn_mfma_f32_16x16x32_f16(af, cf0, o0, 0, 0, 0);
      o1 = __builtin_amdgcn_mfma_f32_16x16x32_f16(af, cf1, o1, 0, 0, 0);
      #pragma unroll
      for (int rg = 0; rg < 4; rg++) {
        int px = (mts + q)*16 + kg*4 + rg;
        int gh = bh0 + (px >> 5), gw = bw0 + (px & 31);
        f16* dst = phi + ((size_t)((img*HD + gh)*WD + gw))*32;
        dst[lr]      = (f16)o0[rg];
        dst[lr + 16] = (f16)o1[rg];
      }
    }
  }
}

// ---------------- neighbor affinity, LDS-tiled ----------------
__device__ __forceinline__ float aff_lds(const f16* __restrict__ sphi, int slot,
                                         f16x8 c0, f16x8 c1, f16x8 c2, f16x8 c3,
                                         bool valid) {
  f16x8 n0 = *(const f16x8*)((const char*)sphi + swz(slot, 0));
  f16x8 n1 = *(const f16x8*)((const char*)sphi + swz(slot, 1));
  f16x8 n2 = *(const f16x8*)((const char*)sphi + swz(slot, 2));
  f16x8 n3 = *(const f16x8*)((const char*)sphi + swz(slot, 3));
  f16x8 d0 = c0 - n0; f16x8 s = d0*d0;
  f16x8 d1 = c1 - n1; s += d1*d1;
  f16x8 d2 = c2 - n2; s += d2*d2;
  f16x8 d3 = c3 - n3; s += d3*d3;
  float d2f = 0.f;
  #pragma unroll
  for (int j = 0; j < 8; j++) d2f += (float)s[j];
  return valid ? __expf(-2.f * d2f) : 0.f;
}

__global__ __launch_bounds__(256, 4) void aff_kernel(const f16* __restrict__ phi, float* __restrict__ wb) {
  __shared__ f16 sphi[612*32];   // 18x34 tile of phi, swizzled

  const int blk  = blockIdx.x;          // 1024
  const int tile = blk & 31;
  const int img  = blk >> 5;
  const int th0  = (tile >> 2) * 16;
  const int tw0  = (tile & 3) * 32;
  const size_t ibase = (size_t)img * HD * WD;

  for (int task = threadIdx.x; task < 2448; task += 256) {
    int p = task >> 2, g = task & 3;
    int r = p / 34, c = p - r*34;
    int gh = min(max(th0 - 1 + r, 0), HD-1);
    int gw = min(max(tw0 - 1 + c, 0), WD-1);
    f16x8 v = *(const f16x8*)(phi + (ibase + gh*WD + gw)*32 + g*8);
    *(f16x8*)((char*)sphi + swz(p, g)) = v;
  }
  __syncthreads();

  for (int p2 = threadIdx.x; p2 < 512; p2 += 256) {
    int r2 = p2 >> 5, c2 = p2 & 31;
    int gh = th0 + r2, gw = tw0 + c2;
    int qc = (r2+1)*34 + (c2+1);
    f16x8 c0 = *(const f16x8*)((const char*)sphi + swz(qc, 0));
    f16x8 c1 = *(const f16x8*)((const char*)sphi + swz(qc, 1));
    f16x8 c2v = *(const f16x8*)((const char*)sphi + swz(qc, 2));
    f16x8 c3 = *(const f16x8*)((const char*)sphi + swz(qc, 3));
    float4 out;
    out.x = aff_lds(sphi, qc + 34, c0,c1,c2v,c3, gh < HD-1);
    out.y = aff_lds(sphi, qc - 34, c0,c1,c2v,c3, gh > 0);
    out.z = aff_lds(sphi, qc + 1,  c0,c1,c2v,c3, gw < WD-1);
    out.w = aff_lds(sphi, qc - 1,  c0,c1,c2v,c3, gw > 0);
    ((float4*)wb)[ibase + gh*WD + gw] = out;
  }
}

// ---------------- analytic A0 accumulate ----------------
__device__ __forceinline__ void a0_accum(float* a, int hh, int ww, float wt) {
  const float fh = (float)hh, fw = (float)ww;
  float e[32]; float s = 0.f;
  #pragma unroll
  for (int kh = 0; kh < 4; kh++) {
    float dh = fh - (float)(kh*32 + 16);
    float dh2 = dh*dh;
    #pragma unroll
    for (int kw = 0; kw < 8; kw++) {
      float dw = fw - (float)(kw*16 + 8);
      float x = __expf(-(dh2 + dw*dw) * (1.f/512.f));
      e[kh*8+kw] = x; s += x;
    }
  }
  float sc = wt / s;
  #pragma unroll
  for (int k = 0; k < 32; k++) a[k] = fmaf(e[k], sc, a[k]);
}

// ---------------- fused pair of message-pass iterations, single-buffer LDS pipeline ----------------
// tile 16x32; buf holds Ain stage (20x36=720 slots) then amid (18x34=612 slots)
template<int FIRST, int LAST>
__global__ __launch_bounds__(256, 3) void mp2_kernel(const f16* __restrict__ Ain,
                                                     const float* __restrict__ wb,
                                                     f16* __restrict__ Aout,
                                                     float* __restrict__ AoutF) {
  __shared__ f16 buf[720*32];   // 46 KB

  const int blk  = blockIdx.x;
  const int cxcd = blk & 7;
  const int q    = blk >> 3;
  const int tile = q & 31;
  const int img  = cxcd + ((q >> 5) << 3);
  const int th0  = (tile >> 2) * 16;
  const int tw0  = (tile & 3) * 32;
  const size_t ibase = (size_t)img * HD * WD;

  // ---- phase 1: stage Ain(20x36), each chunk loaded exactly once, dense coalescing ----
  if (!FIRST) {
    for (int task = threadIdx.x; task < 2880; task += 256) {
      int p = task >> 2, g = task & 3;
      int r = p / 36, c = p - r*36;
      int gh = min(max(th0 - 2 + r, 0), HD-1);
      int gw = min(max(tw0 - 2 + c, 0), WD-1);
      f16x8 v = *(const f16x8*)(Ain + (ibase + gh*WD + gw)*32 + g*8);
      *(f16x8*)((char*)buf + swz(p, g)) = v;
    }
    __syncthreads();
  }

  // ---- phase 2: iter-a into registers (amid 18x34) ----
  f16x8 res[3][4];
  #pragma unroll
  for (int it = 0; it < 3; it++) {
    int p = threadIdx.x + it*256;
    if (p >= 612) continue;
    int r = p / 34, cc = p - r*34;
    int gh = th0 - 1 + r, gw = tw0 - 1 + cc;
    bool inimg = ((unsigned)gh < (unsigned)HD) && ((unsigned)gw < (unsigned)WD);
    int ghc = min(max(gh, 0), HD-1), gwc = min(max(gw, 0), WD-1);
    float4 wd = make_float4(0.f, 0.f, 0.f, 0.f);
    if (inimg) wd = ((const float4*)wb)[ibase + gh*WD + gw];

    int hu = (ghc < HD-1) ? ghc+1 : ghc;
    int hd = (ghc > 0)    ? ghc-1 : ghc;
    int wl = (gwc < WD-1) ? gwc+1 : gwc;
    int wr = (gwc > 0)    ? gwc-1 : gwc;

    float a[32];
    #pragma unroll
    for (int k = 0; k < 32; k++) a[k] = 0.f;

    if (FIRST) {
      a0_accum(a, hu, gwc, wd.x);
      a0_accum(a, hd, gwc, wd.y);
      a0_accum(a, ghc, wl, wd.z);
      a0_accum(a, ghc, wr, wd.w);
    } else {
      int su = (hu - th0 + 2)*36 + (gwc - tw0 + 2);
      int sd = (hd - th0 + 2)*36 + (gwc - tw0 + 2);
      int sl = (ghc - th0 + 2)*36 + (wl - tw0 + 2);
      int sr = (ghc - th0 + 2)*36 + (wr - tw0 + 2);
      f16 w0 = (f16)wd.x, w1 = (f16)wd.y, w2 = (f16)wd.z, w3 = (f16)wd.w;
      #pragma unroll
      for (int g = 0; g < 4; g++) {
        f16x8 v0 = *(const f16x8*)((const char*)buf + swz(su, g));
        f16x8 v1 = *(const f16x8*)((const char*)buf + swz(sd, g));
        f16x8 v2 = *(const f16x8*)((const char*)buf + swz(sl, g));
        f16x8 v3 = *(const f16x8*)((const char*)buf + swz(sr, g));
        #pragma unroll
        for (int j = 0; j < 8; j++) {
          f16 x = v0[j]*w0 + v1[j]*w1 + v2[j]*w2 + v3[j]*w3;
          a[g*8+j] = (float)x;
        }
      }
    }

    float s = 0.f;
    #pragma unroll
    for (int k = 0; k < 32; k++) { a[k] = __expf(a[k] + a[k]); s += a[k]; }
    float inv = 1.f / s;
    #pragma unroll
    for (int g = 0; g < 4; g++) {
      f16x8 o;
      #pragma unroll
      for (int j = 0; j < 8; j++) o[j] = (f16)(a[g*8+j] * inv);
      res[it][g] = o;
    }
  }
  __syncthreads();

  // ---- phase 3: write amid over the stage buffer ----
  #pragma unroll
  for (int it = 0; it < 3; it++) {
    int p = threadIdx.x + it*256;
    if (p >= 612) continue;
    #pragma unroll
    for (int g = 0; g < 4; g++)
      *(f16x8*)((char*)buf + swz(p, g)) = res[it][g];
  }
  __syncthreads();

  // ---- phase 4: iter-b on interior 16x32 from LDS ----
  for (int p2 = threadIdx.x; p2 < 512; p2 += 256) {
    int r2 = p2 >> 5, c2 = p2 & 31;
    int gh = th0 + r2, gw = tw0 + c2;
    int rm = r2 + 1, cm = c2 + 1;
    float4 wd = ((const float4*)wb)[ibase + gh*WD + gw];

    int q0 = (rm + ((gh < HD-1) ? 1 : 0))*34 + cm;
    int q1 = (rm - ((gh > 0)    ? 1 : 0))*34 + cm;
    int q2 = rm*34 + cm + ((gw < WD-1) ? 1 : 0);
    int q3 = rm*34 + cm - ((gw > 0)    ? 1 : 0);

    f16 w0 = (f16)wd.x, w1 = (f16)wd.y, w2 = (f16)wd.z, w3 = (f16)wd.w;
    float a[32];
    #pragma unroll
    for (int g = 0; g < 4; g++) {
      f16x8 v0 = *(const f16x8*)((const char*)buf + swz(q0, g));
      f16x8 v1 = *(const f16x8*)((const char*)buf + swz(q1, g));
      f16x8 v2 = *(const f16x8*)((const char*)buf + swz(q2, g));
      f16x8 v3 = *(const f16x8*)((const char*)buf + swz(q3, g));
      #pragma unroll
      for (int j = 0; j < 8; j++) {
        f16 x = v0[j]*w0 + v1[j]*w1 + v2[j]*w2 + v3[j]*w3;
        a[g*8+j] = (float)x;
      }
    }
    float s = 0.f;
    #pragma unroll
    for (int k = 0; k < 32; k++) { a[k] = __expf(a[k] + a[k]); s += a[k]; }
    float inv = 1.f / s;
    size_t opix = ibase + (size_t)gh*WD + gw;
    if (LAST) {
      float4* dst = (float4*)(AoutF + opix*32);
      #pragma unroll
      for (int g = 0; g < 8; g++)
        dst[g] = make_float4(a[4*g]*inv, a[4*g+1]*inv, a[4*g+2]*inv, a[4*g+3]*inv);
    } else {
      f16x8* dst = (f16x8*)(Aout + opix*32);
      #pragma unroll
      for (int g = 0; g < 4; g++) {
        f16x8 o;
        #pragma unroll
        for (int j = 0; j < 8; j++) o[j] = (f16)(a[g*8+j]*inv);
        dst[g] = o;
      }
    }
  }
}

// ---------------- pooled features, stage 1 ----------------
__global__ __launch_bounds__(256) void pool1_kernel(const float* __restrict__ A,
                                                    const int* __restrict__ X,
                                                    float* __restrict__ part) {
  const int b = blockIdx.x, cy = blockIdx.y;
  const int k = threadIdx.x & 31, sub = threadIdx.x >> 5;
  const int h = cy*4 + (sub >> 1);
  const int w0 = (sub & 1) * 64;
  const float hh = ((float)h + 0.5f) * (1.f/128.f);
  float s0 = 0.f, sw = 0.f, sw2 = 0.f;
  float col[10];
  #pragma unroll
  for (int c = 0; c < 10; c++) col[c] = 0.f;
  const float* Arow = A + ((size_t)((b*HD + h)*WD + w0))*32 + k;
  const int*   Xrow = X + (b*HD + h)*WD + w0;
  for (int w = 0; w < 64; w++) {
    float a  = Arow[(size_t)w*32];
    float ww = ((float)(w + w0) + 0.5f) * (1.f/128.f);
    s0 += a; sw = fmaf(ww, a, sw); sw2 = fmaf(ww*ww, a, sw2);
    int x = Xrow[w];
    #pragma unroll
    for (int c = 0; c < 10; c++) col[c] += (x == c) ? a : 0.f;
  }
  __shared__ float red[8][32][15];
  float vals[15];
  vals[0] = s0; vals[1] = hh*s0; vals[2] = sw; vals[3] = hh*hh*s0; vals[4] = sw2;
  #pragma unroll
  for (int c = 0; c < 10; c++) vals[5+c] = col[c];
  #pragma unroll
  for (int q = 0; q < 15; q++) red[sub][k][q] = vals[q];
  __syncthreads();
  if (sub == 0) {
    #pragma unroll
    for (int q = 0; q < 15; q++) {
      float v = 0.f;
      #pragma unroll
      for (int s2 = 0; s2 < 8; s2++) v += red[s2][k][q];
      part[(((size_t)b*32 + cy)*32 + k)*15 + q] = v;
    }
  }
}

// ---------------- pooled features, stage 2 ----------------
__global__ __launch_bounds__(256) void pool2_kernel(const float* __restrict__ part,
                                                    float* __restrict__ T) {
  const int t = blockIdx.x * 256 + threadIdx.x;
  if (t >= BB*KK) return;
  const int b = t >> 5, k = t & 31;
  float s[15];
  #pragma unroll
  for (int q = 0; q < 15; q++) s[q] = 0.f;
  for (int cy = 0; cy < 32; cy++) {
    const float* p = part + (((size_t)b*32 + cy)*32 + k)*15;
    #pragma unroll
    for (int q = 0; q < 15; q++) s[q] += p[q];
  }
  float mass = s[0] + 1e-6f;
  float inv  = 1.f / mass;
  float h_c = s[1]*inv, w_c = s[2]*inv, h2 = s[3]*inv, w2 = s[4]*inv;
  float h_sd = sqrtf(fmaxf(h2 - h_c*h_c, 0.f) + 1e-6f);
  float w_sd = sqrtf(fmaxf(w2 - w_c*w_c, 0.f) + 1e-6f);
  float* o = T + (size_t)t*17;
  o[0] = mass * (1.f/16384.f);
  o[1] = h_c; o[2] = w_c;
  #pragma unroll
  for (int c = 0; c < 10; c++) o[3+c] = s[5+c]*inv;
  o[13] = h_c - h_sd; o[14] = h_c + h_sd; o[15] = w_c - w_sd; o[16] = w_c + w_sd;
}

extern "C" void kernel_launch(void* const* d_in, const int* in_sizes, int n_in,
                              void* d_out, int out_size, void* d_ws, size_t ws_size,
                              hipStream_t stream) {
  const int*   X  = (const int*)d_in[0];
  const float* w1 = (const float*)d_in[1];
  const float* b1 = (const float*)d_in[2];
  const float* w2 = (const float*)d_in[3];
  const float* b2 = (const float*)d_in[4];
  const float* w3 = (const float*)d_in[5];
  const float* b3 = (const float*)d_in[6];

  float* out   = (float*)d_out;
  float* A_out = out;                           // (B,H,W,K) f32
  float* T_out = out + (size_t)NPIX * KK;       // (B,K,17)

  char*  ws   = (char*)d_ws;
  f16*   bufA = (f16*)ws;                                   // 32 MB: A ping (part aliases later)
  float* wb   = (float*)(ws + (size_t)32*1024*1024);        // 8 MB
  f16*   bufB = (f16*)(ws + (size_t)40*1024*1024);          // 32 MB: phi, then A pong
  float* part = (float*)ws;                                 // aliases bufA (dead at pool time)

  f16* phi = bufB;
  cnn_kernel<<<dim3(WD/32, HD/16, BB), 512, 0, stream>>>(X, w1, b1, w2, b2, w3, b3, phi);
  aff_kernel<<<1024, 256, 0, stream>>>(phi, wb);

  mp2_kernel<1,0><<<1024, 256, 0, stream>>>(nullptr, wb, bufA, nullptr);  // iters 1,2 (analytic A0)
  mp2_kernel<0,0><<<1024, 256, 0, stream>>>(bufA, wb, bufB, nullptr);     // iters 3,4
  mp2_kernel<0,0><<<1024, 256, 0, stream>>>(bufB, wb, bufA, nullptr);     // iters 5,6
  mp2_kernel<0,1><<<1024, 256, 0, stream>>>(bufA, wb, nullptr, A_out);    // iters 7,8 -> f32

  pool1_kernel<<<dim3(BB, 32), 256, 0, stream>>>(A_out, X, part);
  pool2_kernel<<<(BB*KK + 255)/256, 256, 0, stream>>>(part, T_out);
}

// Round 6
// 271.457 us; speedup vs baseline: 1.1327x; 1.1327x over previous
//
#include <hip/hip_runtime.h>
#include <math.h>

#define HD 128
#define WD 128
#define BB 32
#define KK 32
#define NPIX (BB*HD*WD)   // 524288

typedef _Float16 f16;
typedef __attribute__((ext_vector_type(8))) _Float16 f16x8;
typedef __attribute__((ext_vector_type(4))) float f32x4;

// byte offset of 16B chunk g within 64B row; bijective over (row mod 8) -> all 32 banks
__device__ __forceinline__ int swz(int row, int g){
  return row*64 + (((g + (row >> 1)) & 3) << 4);
}

__device__ __forceinline__ float xexp2(float x){
#if __has_builtin(__builtin_amdgcn_exp2f)
  return __builtin_amdgcn_exp2f(x);
#else
  return exp2f(x);
#endif
}
__device__ __forceinline__ float xrcp(float x){
#if __has_builtin(__builtin_amdgcn_rcpf)
  return __builtin_amdgcn_rcpf(x);
#else
  return 1.f/x;
#endif
}
__device__ __forceinline__ f16x8 bc8(f16 x){
  f16x8 v;
  #pragma unroll
  for (int j = 0; j < 8; j++) v[j] = x;
  return v;
}

// ---------------- fused CNN via f16 MFMA (unchanged from R5) ----------------
__global__ __launch_bounds__(512, 2) void cnn_kernel(
    const int* __restrict__ X,
    const float* __restrict__ w1, const float* __restrict__ b1,
    const float* __restrict__ w2, const float* __restrict__ b2,
    const float* __restrict__ w3, const float* __restrict__ b3,
    f16* __restrict__ phi)
{
  __shared__ f16 sW1f[9*11*40];
  __shared__ int   sX[20*36];
  __shared__ float sB2[32], sB3[32];
  __shared__ f16 x1[612*32];
  __shared__ f16 w2t[9*32*32];
  __shared__ f16 w3t[32*32];

  const int tid = threadIdx.x;
  const int img = blockIdx.z;
  const int bh0 = blockIdx.y * 16;
  const int bw0 = blockIdx.x * 32;

  for (int i = tid; i < 9*11*32; i += 512) {
    int tap = i / 352, c = (i % 352) >> 5, oc = i & 31;
    float v = (c < 10) ? w1[tap*320 + c*32 + oc] : 0.f;
    if (tap == 4 && c < 10) v += b1[oc];
    sW1f[(tap*11 + c)*40 + oc] = (f16)v;
  }
  for (int i = tid; i < 9*32*32; i += 512) {
    int tap = i >> 10, ic = (i >> 5) & 31, oc = i & 31;
    int off = swz(tap*32 + oc, ic >> 3) + (ic & 7)*2;
    *(f16*)((char*)w2t + off) = (f16)w2[i];
  }
  for (int i = tid; i < 32*32; i += 512) {
    int ic = i >> 5, oe = i & 31;
    int off = swz(oe, ic >> 3) + (ic & 7)*2;
    *(f16*)((char*)w3t + off) = (f16)w3[i];
  }
  if (tid < 32) { sB2[tid] = b2[tid]; sB3[tid] = b3[tid]; }
  for (int i = tid; i < 20*36; i += 512) {
    int ti = i / 36, tj = i % 36;
    int gh = bh0 - 2 + ti, gw = bw0 - 2 + tj;
    sX[i] = (gh >= 0 && gh < HD && gw >= 0 && gw < WD) ? X[(img*HD + gh)*WD + gw] : 10;
  }
  __syncthreads();

  for (int p = tid; p < 612; p += 512) {
    int hr = p / 34, hc = p - hr*34;
    int gh = bh0 + hr - 1, gw = bw0 + hc - 1;
    if (gh >= 0 && gh < HD && gw >= 0 && gw < WD) {
      f16x8 acc[4];
      {
        int c = sX[hr*36 + hc];
        const f16* wr = &sW1f[c*40];
        #pragma unroll
        for (int g = 0; g < 4; g++) acc[g] = *(const f16x8*)(wr + g*8);
      }
      #pragma unroll
      for (int tap = 1; tap < 9; tap++) {
        const int ti = tap/3, tj = tap%3;
        int c = sX[(hr+ti)*36 + hc + tj];
        const f16* wr = &sW1f[(tap*11 + c)*40];
        #pragma unroll
        for (int g = 0; g < 4; g++) acc[g] += *(const f16x8*)(wr + g*8);
      }
      #pragma unroll
      for (int g = 0; g < 4; g++) {
        f16x8 r = acc[g];
        #pragma unroll
        for (int j = 0; j < 8; j++) r[j] = (r[j] > (f16)0.f) ? r[j] : (f16)0.f;
        *(f16x8*)((char*)x1 + swz(p, g)) = r;
      }
    } else {
      f16x8 z;
      #pragma unroll
      for (int j = 0; j < 8; j++) z[j] = (f16)0.f;
      #pragma unroll
      for (int g = 0; g < 4; g++) *(f16x8*)((char*)x1 + swz(p, g)) = z;
    }
  }
  __syncthreads();

  const int lane = tid & 63;
  const int wv   = tid >> 6;
  const int lr   = lane & 15;
  const int kg   = lane >> 4;
  const int mts  = wv * 4;

  int arow0[4];
  #pragma unroll
  for (int q = 0; q < 4; q++) {
    int px = (mts + q)*16 + lr;
    arow0[q] = (px >> 5)*34 + (px & 31);
  }
  float b2v0 = sB2[lr], b2v1 = sB2[lr + 16];
  f32x4 acc[4][2];
  #pragma unroll
  for (int q = 0; q < 4; q++) {
    acc[q][0] = (f32x4){b2v0, b2v0, b2v0, b2v0};
    acc[q][1] = (f32x4){b2v1, b2v1, b2v1, b2v1};
  }
  #pragma unroll
  for (int tap = 0; tap < 9; tap++) {
    const int ti = tap/3, tj = tap%3;
    f16x8 bf0 = *(const f16x8*)((const char*)w2t + swz(tap*32 + lr,      kg));
    f16x8 bf1 = *(const f16x8*)((const char*)w2t + swz(tap*32 + lr + 16, kg));
    #pragma unroll
    for (int q = 0; q < 4; q++) {
      int row = arow0[q] + ti*34 + tj;
      f16x8 af = *(const f16x8*)((const char*)x1 + swz(row, kg));
      acc[q][0] = __builtin_amdgcn_mfma_f32_16x16x32_f16(af, bf0, acc[q][0], 0, 0, 0);
      acc[q][1] = __builtin_amdgcn_mfma_f32_16x16x32_f16(af, bf1, acc[q][1], 0, 0, 0);
    }
  }
  __syncthreads();

  #pragma unroll
  for (int q = 0; q < 4; q++)
    #pragma unroll
    for (int nt = 0; nt < 2; nt++) {
      int oc = nt*16 + lr;
      #pragma unroll
      for (int rg = 0; rg < 4; rg++) {
        int px = (mts + q)*16 + kg*4 + rg;
        int off = swz(px, oc >> 3) + (oc & 7)*2;
        *(f16*)((char*)x1 + off) = (f16)fmaxf(acc[q][nt][rg], 0.f);
      }
    }
  __syncthreads();

  {
    f16x8 cf0 = *(const f16x8*)((const char*)w3t + swz(lr,      kg));
    f16x8 cf1 = *(const f16x8*)((const char*)w3t + swz(lr + 16, kg));
    float b3v0 = sB3[lr], b3v1 = sB3[lr + 16];
    #pragma unroll
    for (int q = 0; q < 4; q++) {
      f16x8 af = *(const f16x8*)((const char*)x1 + swz((mts + q)*16 + lr, kg));
      f32x4 o0 = (f32x4){b3v0, b3v0, b3v0, b3v0};
      f32x4 o1 = (f32x4){b3v1, b3v1, b3v1, b3v1};
      o0 = __builtin_amdgcn_mfma_f32_16x16x32_f16(af, cf0, o0, 0, 0, 0);
      o1 = __builtin_amdgcn_mfma_f32_16x16x32_f16(af, cf1, o1, 0, 0, 0);
      #pragma unroll
      for (int rg = 0; rg < 4; rg++) {
        int px = (mts + q)*16 + kg*4 + rg;
        int gh = bh0 + (px >> 5), gw = bw0 + (px & 31);
        f16* dst = phi + ((size_t)((img*HD + gh)*WD + gw))*32;
        dst[lr]      = (f16)o0[rg];
        dst[lr + 16] = (f16)o1[rg];
      }
    }
  }
}

// ---------------- neighbor affinity, LDS-tiled; outputs w' = 2*log2e * exp(-2*d2) ----------------
#define WSCALE 2.8853900817779268f   // 2*log2(e)

__device__ __forceinline__ float aff_lds(const f16* __restrict__ sphi, int slot,
                                         f16x8 c0, f16x8 c1, f16x8 c2, f16x8 c3,
                                         bool valid) {
  f16x8 n0 = *(const f16x8*)((const char*)sphi + swz(slot, 0));
  f16x8 n1 = *(const f16x8*)((const char*)sphi + swz(slot, 1));
  f16x8 n2 = *(const f16x8*)((const char*)sphi + swz(slot, 2));
  f16x8 n3 = *(const f16x8*)((const char*)sphi + swz(slot, 3));
  f16x8 d0 = c0 - n0; f16x8 s = d0*d0;
  f16x8 d1 = c1 - n1; s += d1*d1;
  f16x8 d2 = c2 - n2; s += d2*d2;
  f16x8 d3 = c3 - n3; s += d3*d3;
  float d2f = 0.f;
  #pragma unroll
  for (int j = 0; j < 8; j++) d2f += (float)s[j];
  // w' = WSCALE * exp(-2*d2) = WSCALE * exp2(-WSCALE*d2)
  return valid ? WSCALE * xexp2(-WSCALE * d2f) : 0.f;
}

__global__ __launch_bounds__(256, 4) void aff_kernel(const f16* __restrict__ phi, float* __restrict__ wb) {
  __shared__ f16 sphi[612*32];

  const int blk  = blockIdx.x;          // 1024
  const int tile = blk & 31;
  const int img  = blk >> 5;
  const int th0  = (tile >> 2) * 16;
  const int tw0  = (tile & 3) * 32;
  const size_t ibase = (size_t)img * HD * WD;

  for (int task = threadIdx.x; task < 2448; task += 256) {
    int p = task >> 2, g = task & 3;
    int r = p / 34, c = p - r*34;
    int gh = min(max(th0 - 1 + r, 0), HD-1);
    int gw = min(max(tw0 - 1 + c, 0), WD-1);
    f16x8 v = *(const f16x8*)(phi + (ibase + gh*WD + gw)*32 + g*8);
    *(f16x8*)((char*)sphi + swz(p, g)) = v;
  }
  __syncthreads();

  for (int p2 = threadIdx.x; p2 < 512; p2 += 256) {
    int r2 = p2 >> 5, c2 = p2 & 31;
    int gh = th0 + r2, gw = tw0 + c2;
    int qc = (r2+1)*34 + (c2+1);
    f16x8 c0 = *(const f16x8*)((const char*)sphi + swz(qc, 0));
    f16x8 c1 = *(const f16x8*)((const char*)sphi + swz(qc, 1));
    f16x8 c2v = *(const f16x8*)((const char*)sphi + swz(qc, 2));
    f16x8 c3 = *(const f16x8*)((const char*)sphi + swz(qc, 3));
    float4 out;
    out.x = aff_lds(sphi, qc + 34, c0,c1,c2v,c3, gh < HD-1);
    out.y = aff_lds(sphi, qc - 34, c0,c1,c2v,c3, gh > 0);
    out.z = aff_lds(sphi, qc + 1,  c0,c1,c2v,c3, gw < WD-1);
    out.w = aff_lds(sphi, qc - 1,  c0,c1,c2v,c3, gw > 0);
    ((float4*)wb)[ibase + gh*WD + gw] = out;
  }
}

// ---------------- analytic A0 accumulate (separable): a += wt * softmax_k(-d2/512) ----------------
__device__ __forceinline__ void a0_accum2(float* a, int hh, int ww, float wt) {
  const float C = 0.0028177637517362567f;  // log2(e)/512
  float eh[4], ew[8];
  float sh = 0.f, sw = 0.f;
  const float fh = (float)hh, fw = (float)ww;
  #pragma unroll
  for (int kh = 0; kh < 4; kh++) { float d = fh - (float)(kh*32+16); eh[kh] = xexp2(-d*d*C); sh += eh[kh]; }
  #pragma unroll
  for (int kw = 0; kw < 8; kw++) { float d = fw - (float)(kw*16+8); ew[kw] = xexp2(-d*d*C); sw += ew[kw]; }
  float sc = wt * xrcp(sh * sw);
  #pragma unroll
  for (int kh = 0; kh < 4; kh++) {
    float ehs = eh[kh] * sc;
    #pragma unroll
    for (int kw = 0; kw < 8; kw++) a[kh*8+kw] = fmaf(ehs, ew[kw], a[kh*8+kw]);
  }
}

// ---------------- fused message-pass pair: 2 phases, 1 barrier, high occupancy ----------------
// tile 8x32, 256 threads, 2048 blocks; amid (10x34) in LDS (21.8 KB)
template<int FIRST, int LAST>
__global__ __launch_bounds__(256, 6) void mp2_kernel(const f16* __restrict__ Ain,
                                                     const float* __restrict__ wb,
                                                     f16* __restrict__ Aout,
                                                     float* __restrict__ AoutF) {
  __shared__ f16 amid[340*32];   // 10x34 px, swizzled 64B rows

  const int blk  = blockIdx.x;
  const int xcd  = blk & 7;
  const int q    = blk >> 3;                 // 0..255
  const int img  = xcd + ((q >> 6) << 3);    // 4 images per XCD
  const int tile = q & 63;
  const int th0  = (tile >> 2) * 8;
  const int tw0  = (tile & 3) * 32;
  const size_t ibase = (size_t)img * HD * WD;

  // ---- phase A: amid 10x34 (1-px halo), neighbors direct from global/L2 ----
  for (int p = threadIdx.x; p < 340; p += 256) {
    int r = p / 34, cc = p - r*34;
    int gh = th0 - 1 + r, gw = tw0 - 1 + cc;
    bool inimg = ((unsigned)gh < (unsigned)HD) && ((unsigned)gw < (unsigned)WD);
    int ghc = min(max(gh, 0), HD-1), gwc = min(max(gw, 0), WD-1);
    float4 wd = inimg ? ((const float4*)wb)[ibase + gh*WD + gw] : make_float4(0.f,0.f,0.f,0.f);
    int hu = ghc + ((ghc < HD-1) ? 1 : 0);
    int hd = ghc - ((ghc > 0)    ? 1 : 0);
    int wl = gwc + ((gwc < WD-1) ? 1 : 0);
    int wr = gwc - ((gwc > 0)    ? 1 : 0);

    float s = 0.f;
    f16x8 pe[4];
    if (FIRST) {
      float a[32];
      #pragma unroll
      for (int k = 0; k < 32; k++) a[k] = 0.f;
      a0_accum2(a, hu, gwc, wd.x);
      a0_accum2(a, hd, gwc, wd.y);
      a0_accum2(a, ghc, wl, wd.z);
      a0_accum2(a, ghc, wr, wd.w);
      #pragma unroll
      for (int g = 0; g < 4; g++)
        #pragma unroll
        for (int j = 0; j < 8; j++) { float e = xexp2(a[g*8+j]); s += e; pe[g][j] = (f16)e; }
    } else {
      const f16x8* s0 = (const f16x8*)(Ain + (ibase + (size_t)hu*WD + gwc)*32);
      const f16x8* s1 = (const f16x8*)(Ain + (ibase + (size_t)hd*WD + gwc)*32);
      const f16x8* s2 = (const f16x8*)(Ain + (ibase + (size_t)ghc*WD + wl)*32);
      const f16x8* s3 = (const f16x8*)(Ain + (ibase + (size_t)ghc*WD + wr)*32);
      f16x8 w0 = bc8((f16)wd.x), w1 = bc8((f16)wd.y), w2 = bc8((f16)wd.z), w3 = bc8((f16)wd.w);
      #pragma unroll
      for (int g = 0; g < 4; g++) {
        f16x8 agg = s0[g]*w0 + s1[g]*w1 + s2[g]*w2 + s3[g]*w3;
        #pragma unroll
        for (int j = 0; j < 8; j++) { float e = xexp2((float)agg[j]); s += e; pe[g][j] = (f16)e; }
      }
    }
    f16x8 iv = bc8((f16)xrcp(s));
    #pragma unroll
    for (int g = 0; g < 4; g++)
      *(f16x8*)((char*)amid + swz(p, g)) = pe[g]*iv;
  }
  __syncthreads();

  // ---- phase B: interior 8x32, 1 px/thread, read amid from LDS ----
  {
    int r2 = threadIdx.x >> 5, c2 = threadIdx.x & 31;
    int gh = th0 + r2, gw = tw0 + c2;
    int rm = r2 + 1, cm = c2 + 1;
    float4 wd = ((const float4*)wb)[ibase + gh*WD + gw];
    int q0 = (rm + ((gh < HD-1) ? 1 : 0))*34 + cm;
    int q1 = (rm - ((gh > 0)    ? 1 : 0))*34 + cm;
    int q2 = rm*34 + cm + ((gw < WD-1) ? 1 : 0);
    int q3 = rm*34 + cm - ((gw > 0)    ? 1 : 0);
    f16x8 w0 = bc8((f16)wd.x), w1 = bc8((f16)wd.y), w2 = bc8((f16)wd.z), w3 = bc8((f16)wd.w);
    float s = 0.f;
    f16x8 pe[4];
    #pragma unroll
    for (int g = 0; g < 4; g++) {
      f16x8 v0 = *(const f16x8*)((const char*)amid + swz(q0, g));
      f16x8 v1 = *(const f16x8*)((const char*)amid + swz(q1, g));
      f16x8 v2 = *(const f16x8*)((const char*)amid + swz(q2, g));
      f16x8 v3 = *(const f16x8*)((const char*)amid + swz(q3, g));
      f16x8 agg = v0*w0 + v1*w1 + v2*w2 + v3*w3;
      #pragma unroll
      for (int j = 0; j < 8; j++) { float e = xexp2((float)agg[j]); s += e; pe[g][j] = (f16)e; }
    }
    float inv = xrcp(s);
    size_t opix = ibase + (size_t)gh*WD + gw;
    if (LAST) {
      float4* dst = (float4*)(AoutF + opix*32);
      #pragma unroll
      for (int g = 0; g < 4; g++) {
        float4 o1, o2;
        o1.x = (float)pe[g][0]*inv; o1.y = (float)pe[g][1]*inv;
        o1.z = (float)pe[g][2]*inv; o1.w = (float)pe[g][3]*inv;
        o2.x = (float)pe[g][4]*inv; o2.y = (float)pe[g][5]*inv;
        o2.z = (float)pe[g][6]*inv; o2.w = (float)pe[g][7]*inv;
        dst[2*g] = o1; dst[2*g+1] = o2;
      }
    } else {
      f16x8 iv = bc8((f16)inv);
      f16x8* dst = (f16x8*)(Aout + opix*32);
      #pragma unroll
      for (int g = 0; g < 4; g++) dst[g] = pe[g]*iv;
    }
  }
}

// ---------------- pooled features, stage 1 ----------------
__global__ __launch_bounds__(256) void pool1_kernel(const float* __restrict__ A,
                                                    const int* __restrict__ X,
                                                    float* __restrict__ part) {
  const int b = blockIdx.x, cy = blockIdx.y;
  const int k = threadIdx.x & 31, sub = threadIdx.x >> 5;
  const int h = cy*4 + (sub >> 1);
  const int w0 = (sub & 1) * 64;
  const float hh = ((float)h + 0.5f) * (1.f/128.f);
  float s0 = 0.f, sw = 0.f, sw2 = 0.f;
  float col[10];
  #pragma unroll
  for (int c = 0; c < 10; c++) col[c] = 0.f;
  const float* Arow = A + ((size_t)((b*HD + h)*WD + w0))*32 + k;
  const int*   Xrow = X + (b*HD + h)*WD + w0;
  for (int w = 0; w < 64; w++) {
    float a  = Arow[(size_t)w*32];
    float ww = ((float)(w + w0) + 0.5f) * (1.f/128.f);
    s0 += a; sw = fmaf(ww, a, sw); sw2 = fmaf(ww*ww, a, sw2);
    int x = Xrow[w];
    #pragma unroll
    for (int c = 0; c < 10; c++) col[c] += (x == c) ? a : 0.f;
  }
  __shared__ float red[8][32][15];
  float vals[15];
  vals[0] = s0; vals[1] = hh*s0; vals[2] = sw; vals[3] = hh*hh*s0; vals[4] = sw2;
  #pragma unroll
  for (int c = 0; c < 10; c++) vals[5+c] = col[c];
  #pragma unroll
  for (int q = 0; q < 15; q++) red[sub][k][q] = vals[q];
  __syncthreads();
  if (sub == 0) {
    #pragma unroll
    for (int q = 0; q < 15; q++) {
      float v = 0.f;
      #pragma unroll
      for (int s2 = 0; s2 < 8; s2++) v += red[s2][k][q];
      part[(((size_t)b*32 + cy)*32 + k)*15 + q] = v;
    }
  }
}

// ---------------- pooled features, stage 2 ----------------
__global__ __launch_bounds__(256) void pool2_kernel(const float* __restrict__ part,
                                                    float* __restrict__ T) {
  const int t = blockIdx.x * 256 + threadIdx.x;
  if (t >= BB*KK) return;
  const int b = t >> 5, k = t & 31;
  float s[15];
  #pragma unroll
  for (int q = 0; q < 15; q++) s[q] = 0.f;
  for (int cy = 0; cy < 32; cy++) {
    const float* p = part + (((size_t)b*32 + cy)*32 + k)*15;
    #pragma unroll
    for (int q = 0; q < 15; q++) s[q] += p[q];
  }
  float mass = s[0] + 1e-6f;
  float inv  = 1.f / mass;
  float h_c = s[1]*inv, w_c = s[2]*inv, h2 = s[3]*inv, w2 = s[4]*inv;
  float h_sd = sqrtf(fmaxf(h2 - h_c*h_c, 0.f) + 1e-6f);
  float w_sd = sqrtf(fmaxf(w2 - w_c*w_c, 0.f) + 1e-6f);
  float* o = T + (size_t)t*17;
  o[0] = mass * (1.f/16384.f);
  o[1] = h_c; o[2] = w_c;
  #pragma unroll
  for (int c = 0; c < 10; c++) o[3+c] = s[5+c]*inv;
  o[13] = h_c - h_sd; o[14] = h_c + h_sd; o[15] = w_c - w_sd; o[16] = w_c + w_sd;
}

extern "C" void kernel_launch(void* const* d_in, const int* in_sizes, int n_in,
                              void* d_out, int out_size, void* d_ws, size_t ws_size,
                              hipStream_t stream) {
  const int*   X  = (const int*)d_in[0];
  const float* w1 = (const float*)d_in[1];
  const float* b1 = (const float*)d_in[2];
  const float* w2 = (const float*)d_in[3];
  const float* b2 = (const float*)d_in[4];
  const float* w3 = (const float*)d_in[5];
  const float* b3 = (const float*)d_in[6];

  float* out   = (float*)d_out;
  float* A_out = out;                           // (B,H,W,K) f32
  float* T_out = out + (size_t)NPIX * KK;       // (B,K,17)

  char*  ws   = (char*)d_ws;
  f16*   bufA = (f16*)ws;                                   // 32 MB: A ping (part aliases later)
  float* wb   = (float*)(ws + (size_t)32*1024*1024);        // 8 MB (pre-scaled w')
  f16*   bufB = (f16*)(ws + (size_t)40*1024*1024);          // 32 MB: phi, then A pong
  float* part = (float*)ws;                                 // aliases bufA (dead at pool time)

  f16* phi = bufB;
  cnn_kernel<<<dim3(WD/32, HD/16, BB), 512, 0, stream>>>(X, w1, b1, w2, b2, w3, b3, phi);
  aff_kernel<<<1024, 256, 0, stream>>>(phi, wb);

  mp2_kernel<1,0><<<2048, 256, 0, stream>>>(nullptr, wb, bufA, nullptr);  // iters 1,2 (analytic A0)
  mp2_kernel<0,0><<<2048, 256, 0, stream>>>(bufA, wb, bufB, nullptr);     // iters 3,4
  mp2_kernel<0,0><<<2048, 256, 0, stream>>>(bufB, wb, bufA, nullptr);     // iters 5,6
  mp2_kernel<0,1><<<2048, 256, 0, stream>>>(bufA, wb, nullptr, A_out);    // iters 7,8 -> f32

  pool1_kernel<<<dim3(BB, 32), 256, 0, stream>>>(A_out, X, part);
  pool2_kernel<<<(BB*KK + 255)/256, 256, 0, stream>>>(part, T_out);
}

// Round 7
// 269.794 us; speedup vs baseline: 1.1397x; 1.0062x over previous
//
#include <hip/hip_runtime.h>
#include <math.h>

#define HD 128
#define WD 128
#define BB 32
#define KK 32
#define NPIX (BB*HD*WD)   // 524288
#define PLANE ((size_t)NPIX*8)   // f16 elems per plane

typedef _Float16 f16;
typedef __attribute__((ext_vector_type(8))) _Float16 f16x8;
typedef __attribute__((ext_vector_type(4))) float f32x4;

// byte offset of 16B chunk g within 64B row; bijective over (row mod 8) -> all 32 banks
__device__ __forceinline__ int swz(int row, int g){
  return row*64 + (((g + (row >> 1)) & 3) << 4);
}

__device__ __forceinline__ float xexp2(float x){
#if __has_builtin(__builtin_amdgcn_exp2f)
  return __builtin_amdgcn_exp2f(x);
#else
  return exp2f(x);
#endif
}
__device__ __forceinline__ float xrcp(float x){
#if __has_builtin(__builtin_amdgcn_rcpf)
  return __builtin_amdgcn_rcpf(x);
#else
  return 1.f/x;
#endif
}
__device__ __forceinline__ f16x8 bc8(f16 x){
  f16x8 v;
  #pragma unroll
  for (int j = 0; j < 8; j++) v[j] = x;
  return v;
}

// ---------------- fused CNN via f16 MFMA (unchanged from R6) ----------------
__global__ __launch_bounds__(512, 2) void cnn_kernel(
    const int* __restrict__ X,
    const float* __restrict__ w1, const float* __restrict__ b1,
    const float* __restrict__ w2, const float* __restrict__ b2,
    const float* __restrict__ w3, const float* __restrict__ b3,
    f16* __restrict__ phi)
{
  __shared__ f16 sW1f[9*11*40];
  __shared__ int   sX[20*36];
  __shared__ float sB2[32], sB3[32];
  __shared__ f16 x1[612*32];
  __shared__ f16 w2t[9*32*32];
  __shared__ f16 w3t[32*32];

  const int tid = threadIdx.x;
  const int img = blockIdx.z;
  const int bh0 = blockIdx.y * 16;
  const int bw0 = blockIdx.x * 32;

  for (int i = tid; i < 9*11*32; i += 512) {
    int tap = i / 352, c = (i % 352) >> 5, oc = i & 31;
    float v = (c < 10) ? w1[tap*320 + c*32 + oc] : 0.f;
    if (tap == 4 && c < 10) v += b1[oc];
    sW1f[(tap*11 + c)*40 + oc] = (f16)v;
  }
  for (int i = tid; i < 9*32*32; i += 512) {
    int tap = i >> 10, ic = (i >> 5) & 31, oc = i & 31;
    int off = swz(tap*32 + oc, ic >> 3) + (ic & 7)*2;
    *(f16*)((char*)w2t + off) = (f16)w2[i];
  }
  for (int i = tid; i < 32*32; i += 512) {
    int ic = i >> 5, oe = i & 31;
    int off = swz(oe, ic >> 3) + (ic & 7)*2;
    *(f16*)((char*)w3t + off) = (f16)w3[i];
  }
  if (tid < 32) { sB2[tid] = b2[tid]; sB3[tid] = b3[tid]; }
  for (int i = tid; i < 20*36; i += 512) {
    int ti = i / 36, tj = i % 36;
    int gh = bh0 - 2 + ti, gw = bw0 - 2 + tj;
    sX[i] = (gh >= 0 && gh < HD && gw >= 0 && gw < WD) ? X[(img*HD + gh)*WD + gw] : 10;
  }
  __syncthreads();

  for (int p = tid; p < 612; p += 512) {
    int hr = p / 34, hc = p - hr*34;
    int gh = bh0 + hr - 1, gw = bw0 + hc - 1;
    if (gh >= 0 && gh < HD && gw >= 0 && gw < WD) {
      f16x8 acc[4];
      {
        int c = sX[hr*36 + hc];
        const f16* wr = &sW1f[c*40];
        #pragma unroll
        for (int g = 0; g < 4; g++) acc[g] = *(const f16x8*)(wr + g*8);
      }
      #pragma unroll
      for (int tap = 1; tap < 9; tap++) {
        const int ti = tap/3, tj = tap%3;
        int c = sX[(hr+ti)*36 + hc + tj];
        const f16* wr = &sW1f[(tap*11 + c)*40];
        #pragma unroll
        for (int g = 0; g < 4; g++) acc[g] += *(const f16x8*)(wr + g*8);
      }
      #pragma unroll
      for (int g = 0; g < 4; g++) {
        f16x8 r = acc[g];
        #pragma unroll
        for (int j = 0; j < 8; j++) r[j] = (r[j] > (f16)0.f) ? r[j] : (f16)0.f;
        *(f16x8*)((char*)x1 + swz(p, g)) = r;
      }
    } else {
      f16x8 z;
      #pragma unroll
      for (int j = 0; j < 8; j++) z[j] = (f16)0.f;
      #pragma unroll
      for (int g = 0; g < 4; g++) *(f16x8*)((char*)x1 + swz(p, g)) = z;
    }
  }
  __syncthreads();

  const int lane = tid & 63;
  const int wv   = tid >> 6;
  const int lr   = lane & 15;
  const int kg   = lane >> 4;
  const int mts  = wv * 4;

  int arow0[4];
  #pragma unroll
  for (int q = 0; q < 4; q++) {
    int px = (mts + q)*16 + lr;
    arow0[q] = (px >> 5)*34 + (px & 31);
  }
  float b2v0 = sB2[lr], b2v1 = sB2[lr + 16];
  f32x4 acc[4][2];
  #pragma unroll
  for (int q = 0; q < 4; q++) {
    acc[q][0] = (f32x4){b2v0, b2v0, b2v0, b2v0};
    acc[q][1] = (f32x4){b2v1, b2v1, b2v1, b2v1};
  }
  #pragma unroll
  for (int tap = 0; tap < 9; tap++) {
    const int ti = tap/3, tj = tap%3;
    f16x8 bf0 = *(const f16x8*)((const char*)w2t + swz(tap*32 + lr,      kg));
    f16x8 bf1 = *(const f16x8*)((const char*)w2t + swz(tap*32 + lr + 16, kg));
    #pragma unroll
    for (int q = 0; q < 4; q++) {
      int row = arow0[q] + ti*34 + tj;
      f16x8 af = *(const f16x8*)((const char*)x1 + swz(row, kg));
      acc[q][0] = __builtin_amdgcn_mfma_f32_16x16x32_f16(af, bf0, acc[q][0], 0, 0, 0);
      acc[q][1] = __builtin_amdgcn_mfma_f32_16x16x32_f16(af, bf1, acc[q][1], 0, 0, 0);
    }
  }
  __syncthreads();

  #pragma unroll
  for (int q = 0; q < 4; q++)
    #pragma unroll
    for (int nt = 0; nt < 2; nt++) {
      int oc = nt*16 + lr;
      #pragma unroll
      for (int rg = 0; rg < 4; rg++) {
        int px = (mts + q)*16 + kg*4 + rg;
        int off = swz(px, oc >> 3) + (oc & 7)*2;
        *(f16*)((char*)x1 + off) = (f16)fmaxf(acc[q][nt][rg], 0.f);
      }
    }
  __syncthreads();

  {
    f16x8 cf0 = *(const f16x8*)((const char*)w3t + swz(lr,      kg));
    f16x8 cf1 = *(const f16x8*)((const char*)w3t + swz(lr + 16, kg));
    float b3v0 = sB3[lr], b3v1 = sB3[lr + 16];
    #pragma unroll
    for (int q = 0; q < 4; q++) {
      f16x8 af = *(const f16x8*)((const char*)x1 + swz((mts + q)*16 + lr, kg));
      f32x4 o0 = (f32x4){b3v0, b3v0, b3v0, b3v0};
      f32x4 o1 = (f32x4){b3v1, b3v1, b3v1, b3v1};
      o0 = __builtin_amdgcn_mfma_f32_16x16x32_f16(af, cf0, o0, 0, 0, 0);
      o1 = __builtin_amdgcn_mfma_f32_16x16x32_f16(af, cf1, o1, 0, 0, 0);
      #pragma unroll
      for (int rg = 0; rg < 4; rg++) {
        int px = (mts + q)*16 + kg*4 + rg;
        int gh = bh0 + (px >> 5), gw = bw0 + (px & 31);
        f16* dst = phi + ((size_t)((img*HD + gh)*WD + gw))*32;
        dst[lr]      = (f16)o0[rg];
        dst[lr + 16] = (f16)o1[rg];
      }
    }
  }
}

// ---------------- neighbor affinity, LDS-tiled; outputs w' = 2*log2e * exp(-2*d2) ----------------
#define WSCALE 2.8853900817779268f   // 2*log2(e)

__device__ __forceinline__ float aff_lds(const f16* __restrict__ sphi, int slot,
                                         f16x8 c0, f16x8 c1, f16x8 c2, f16x8 c3,
                                         bool valid) {
  f16x8 n0 = *(const f16x8*)((const char*)sphi + swz(slot, 0));
  f16x8 n1 = *(const f16x8*)((const char*)sphi + swz(slot, 1));
  f16x8 n2 = *(const f16x8*)((const char*)sphi + swz(slot, 2));
  f16x8 n3 = *(const f16x8*)((const char*)sphi + swz(slot, 3));
  f16x8 d0 = c0 - n0; f16x8 s = d0*d0;
  f16x8 d1 = c1 - n1; s += d1*d1;
  f16x8 d2 = c2 - n2; s += d2*d2;
  f16x8 d3 = c3 - n3; s += d3*d3;
  float d2f = 0.f;
  #pragma unroll
  for (int j = 0; j < 8; j++) d2f += (float)s[j];
  return valid ? WSCALE * xexp2(-WSCALE * d2f) : 0.f;
}

__global__ __launch_bounds__(256, 4) void aff_kernel(const f16* __restrict__ phi, float* __restrict__ wb) {
  __shared__ f16 sphi[612*32];

  const int blk  = blockIdx.x;          // 1024
  const int tile = blk & 31;
  const int img  = blk >> 5;
  const int th0  = (tile >> 2) * 16;
  const int tw0  = (tile & 3) * 32;
  const size_t ibase = (size_t)img * HD * WD;

  for (int task = threadIdx.x; task < 2448; task += 256) {
    int p = task >> 2, g = task & 3;
    int r = p / 34, c = p - r*34;
    int gh = min(max(th0 - 1 + r, 0), HD-1);
    int gw = min(max(tw0 - 1 + c, 0), WD-1);
    f16x8 v = *(const f16x8*)(phi + (ibase + gh*WD + gw)*32 + g*8);
    *(f16x8*)((char*)sphi + swz(p, g)) = v;
  }
  __syncthreads();

  for (int p2 = threadIdx.x; p2 < 512; p2 += 256) {
    int r2 = p2 >> 5, c2 = p2 & 31;
    int gh = th0 + r2, gw = tw0 + c2;
    int qc = (r2+1)*34 + (c2+1);
    f16x8 c0 = *(const f16x8*)((const char*)sphi + swz(qc, 0));
    f16x8 c1 = *(const f16x8*)((const char*)sphi + swz(qc, 1));
    f16x8 c2v = *(const f16x8*)((const char*)sphi + swz(qc, 2));
    f16x8 c3 = *(const f16x8*)((const char*)sphi + swz(qc, 3));
    float4 out;
    out.x = aff_lds(sphi, qc + 34, c0,c1,c2v,c3, gh < HD-1);
    out.y = aff_lds(sphi, qc - 34, c0,c1,c2v,c3, gh > 0);
    out.z = aff_lds(sphi, qc + 1,  c0,c1,c2v,c3, gw < WD-1);
    out.w = aff_lds(sphi, qc - 1,  c0,c1,c2v,c3, gw > 0);
    ((float4*)wb)[ibase + gh*WD + gw] = out;
  }
}

// ---------------- analytic A0 accumulate (separable) ----------------
__device__ __forceinline__ void a0_accum2(float* a, int hh, int ww, float wt) {
  const float C = 0.0028177637517362567f;  // log2(e)/512
  float eh[4], ew[8];
  float sh = 0.f, sw = 0.f;
  const float fh = (float)hh, fw = (float)ww;
  #pragma unroll
  for (int kh = 0; kh < 4; kh++) { float d = fh - (float)(kh*32+16); eh[kh] = xexp2(-d*d*C); sh += eh[kh]; }
  #pragma unroll
  for (int kw = 0; kw < 8; kw++) { float d = fw - (float)(kw*16+8); ew[kw] = xexp2(-d*d*C); sw += ew[kw]; }
  float sc = wt * xrcp(sh * sw);
  #pragma unroll
  for (int kh = 0; kh < 4; kh++) {
    float ehs = eh[kh] * sc;
    #pragma unroll
    for (int kw = 0; kw < 8; kw++) a[kh*8+kw] = fmaf(ehs, ew[kw], a[kh*8+kw]);
  }
}

// ---------------- fused message-pass pair; A stored plane-major A[g][px][8] ----------------
// tile 8x32, 256 threads, 2048 blocks; amid (10x34) in LDS
template<int FIRST>
__global__ __launch_bounds__(256, 6) void mp2_kernel(const f16* __restrict__ Ain,
                                                     const float* __restrict__ wb,
                                                     f16* __restrict__ Aout) {
  __shared__ f16 amid[340*32];

  const int blk  = blockIdx.x;
  const int xcd  = blk & 7;
  const int q    = blk >> 3;
  const int img  = xcd + ((q >> 6) << 3);
  const int tile = q & 63;
  const int th0  = (tile >> 2) * 8;
  const int tw0  = (tile & 3) * 32;
  const size_t ibase = (size_t)img * HD * WD;

  // ---- phase A: amid 10x34 (1-px halo), neighbors from plane-major global (coalesced) ----
  for (int p = threadIdx.x; p < 340; p += 256) {
    int r = p / 34, cc = p - r*34;
    int gh = th0 - 1 + r, gw = tw0 - 1 + cc;
    bool inimg = ((unsigned)gh < (unsigned)HD) && ((unsigned)gw < (unsigned)WD);
    int ghc = min(max(gh, 0), HD-1), gwc = min(max(gw, 0), WD-1);
    float4 wd = inimg ? ((const float4*)wb)[ibase + gh*WD + gw] : make_float4(0.f,0.f,0.f,0.f);
    int hu = ghc + ((ghc < HD-1) ? 1 : 0);
    int hd = ghc - ((ghc > 0)    ? 1 : 0);
    int wl = gwc + ((gwc < WD-1) ? 1 : 0);
    int wr = gwc - ((gwc > 0)    ? 1 : 0);

    float s = 0.f;
    f16x8 pe[4];
    if (FIRST) {
      float a[32];
      #pragma unroll
      for (int k = 0; k < 32; k++) a[k] = 0.f;
      a0_accum2(a, hu, gwc, wd.x);
      a0_accum2(a, hd, gwc, wd.y);
      a0_accum2(a, ghc, wl, wd.z);
      a0_accum2(a, ghc, wr, wd.w);
      #pragma unroll
      for (int g = 0; g < 4; g++)
        #pragma unroll
        for (int j = 0; j < 8; j++) { float e = xexp2(a[g*8+j]); s += e; pe[g][j] = (f16)e; }
    } else {
      const size_t iu_ = ibase + (size_t)hu*WD + gwc;
      const size_t id_ = ibase + (size_t)hd*WD + gwc;
      const size_t il_ = ibase + (size_t)ghc*WD + wl;
      const size_t ir_ = ibase + (size_t)ghc*WD + wr;
      f16x8 w0 = bc8((f16)wd.x), w1 = bc8((f16)wd.y), w2 = bc8((f16)wd.z), w3 = bc8((f16)wd.w);
      #pragma unroll
      for (int g = 0; g < 4; g++) {
        const f16* pg = Ain + (size_t)g*PLANE;
        f16x8 v0 = *(const f16x8*)(pg + iu_*8);
        f16x8 v1 = *(const f16x8*)(pg + id_*8);
        f16x8 v2 = *(const f16x8*)(pg + il_*8);
        f16x8 v3 = *(const f16x8*)(pg + ir_*8);
        f16x8 agg = v0*w0 + v1*w1 + v2*w2 + v3*w3;
        #pragma unroll
        for (int j = 0; j < 8; j++) { float e = xexp2((float)agg[j]); s += e; pe[g][j] = (f16)e; }
      }
    }
    f16x8 iv = bc8((f16)xrcp(s));
    #pragma unroll
    for (int g = 0; g < 4; g++)
      *(f16x8*)((char*)amid + swz(p, g)) = pe[g]*iv;
  }
  __syncthreads();

  // ---- phase B: interior 8x32, 1 px/thread; plane-major coalesced stores ----
  {
    int r2 = threadIdx.x >> 5, c2 = threadIdx.x & 31;
    int gh = th0 + r2, gw = tw0 + c2;
    int rm = r2 + 1, cm = c2 + 1;
    float4 wd = ((const float4*)wb)[ibase + gh*WD + gw];
    int q0 = (rm + ((gh < HD-1) ? 1 : 0))*34 + cm;
    int q1 = (rm - ((gh > 0)    ? 1 : 0))*34 + cm;
    int q2 = rm*34 + cm + ((gw < WD-1) ? 1 : 0);
    int q3 = rm*34 + cm - ((gw > 0)    ? 1 : 0);
    f16x8 w0 = bc8((f16)wd.x), w1 = bc8((f16)wd.y), w2 = bc8((f16)wd.z), w3 = bc8((f16)wd.w);
    float s = 0.f;
    f16x8 pe[4];
    #pragma unroll
    for (int g = 0; g < 4; g++) {
      f16x8 v0 = *(const f16x8*)((const char*)amid + swz(q0, g));
      f16x8 v1 = *(const f16x8*)((const char*)amid + swz(q1, g));
      f16x8 v2 = *(const f16x8*)((const char*)amid + swz(q2, g));
      f16x8 v3 = *(const f16x8*)((const char*)amid + swz(q3, g));
      f16x8 agg = v0*w0 + v1*w1 + v2*w2 + v3*w3;
      #pragma unroll
      for (int j = 0; j < 8; j++) { float e = xexp2((float)agg[j]); s += e; pe[g][j] = (f16)e; }
    }
    f16x8 iv = bc8((f16)xrcp(s));
    size_t opix = ibase + (size_t)gh*WD + gw;
    #pragma unroll
    for (int g = 0; g < 4; g++)
      *(f16x8*)(Aout + (size_t)g*PLANE + opix*8) = pe[g]*iv;
  }
}

// ---------------- convert planes -> canonical f32 A (coalesced writes) ----------------
__global__ __launch_bounds__(256) void conv_kernel(const f16* __restrict__ Ap,
                                                   float* __restrict__ Aout) {
  const int t = blockIdx.x * 256 + threadIdx.x;   // NPIX*4
  const int px = t >> 2, g = t & 3;
  f16x8 v = *(const f16x8*)(Ap + (size_t)g*PLANE + (size_t)px*8);
  float4 o0, o1;
  o0.x = (float)v[0]; o0.y = (float)v[1]; o0.z = (float)v[2]; o0.w = (float)v[3];
  o1.x = (float)v[4]; o1.y = (float)v[5]; o1.z = (float)v[6]; o1.w = (float)v[7];
  float4* dst = (float4*)(Aout + (size_t)px*32 + g*8);
  dst[0] = o0; dst[1] = o1;
}

// ---------------- pooled features, stage 1 (reads f16 planes) ----------------
__global__ __launch_bounds__(256) void pool1_kernel(const f16* __restrict__ Ap,
                                                    const int* __restrict__ X,
                                                    float* __restrict__ part) {
  const int b = blockIdx.x, cy = blockIdx.y;
  const int k = threadIdx.x & 31, sub = threadIdx.x >> 5;
  const int h = cy*4 + (sub >> 1);
  const int w0 = (sub & 1) * 64;
  const float hh = ((float)h + 0.5f) * (1.f/128.f);
  float s0 = 0.f, sw = 0.f, sw2 = 0.f;
  float col[10];
  #pragma unroll
  for (int c = 0; c < 10; c++) col[c] = 0.f;
  const f16* pl = Ap + (size_t)(k >> 3)*PLANE + ((size_t)((b*HD + h)*WD + w0))*8 + (k & 7);
  const int* Xrow = X + (b*HD + h)*WD + w0;
  for (int w = 0; w < 64; w++) {
    float a  = (float)pl[w*8];
    float ww = ((float)(w + w0) + 0.5f) * (1.f/128.f);
    s0 += a; sw = fmaf(ww, a, sw); sw2 = fmaf(ww*ww, a, sw2);
    int x = Xrow[w];
    #pragma unroll
    for (int c = 0; c < 10; c++) col[c] += (x == c) ? a : 0.f;
  }
  __shared__ float red[8][32][15];
  float vals[15];
  vals[0] = s0; vals[1] = hh*s0; vals[2] = sw; vals[3] = hh*hh*s0; vals[4] = sw2;
  #pragma unroll
  for (int c = 0; c < 10; c++) vals[5+c] = col[c];
  #pragma unroll
  for (int q = 0; q < 15; q++) red[sub][k][q] = vals[q];
  __syncthreads();
  if (sub == 0) {
    #pragma unroll
    for (int q = 0; q < 15; q++) {
      float v = 0.f;
      #pragma unroll
      for (int s2 = 0; s2 < 8; s2++) v += red[s2][k][q];
      part[(((size_t)b*32 + cy)*32 + k)*15 + q] = v;
    }
  }
}

// ---------------- pooled features, stage 2 ----------------
__global__ __launch_bounds__(256) void pool2_kernel(const float* __restrict__ part,
                                                    float* __restrict__ T) {
  const int t = blockIdx.x * 256 + threadIdx.x;
  if (t >= BB*KK) return;
  const int b = t >> 5, k = t & 31;
  float s[15];
  #pragma unroll
  for (int q = 0; q < 15; q++) s[q] = 0.f;
  for (int cy = 0; cy < 32; cy++) {
    const float* p = part + (((size_t)b*32 + cy)*32 + k)*15;
    #pragma unroll
    for (int q = 0; q < 15; q++) s[q] += p[q];
  }
  float mass = s[0] + 1e-6f;
  float inv  = 1.f / mass;
  float h_c = s[1]*inv, w_c = s[2]*inv, h2 = s[3]*inv, w2 = s[4]*inv;
  float h_sd = sqrtf(fmaxf(h2 - h_c*h_c, 0.f) + 1e-6f);
  float w_sd = sqrtf(fmaxf(w2 - w_c*w_c, 0.f) + 1e-6f);
  float* o = T + (size_t)t*17;
  o[0] = mass * (1.f/16384.f);
  o[1] = h_c; o[2] = w_c;
  #pragma unroll
  for (int c = 0; c < 10; c++) o[3+c] = s[5+c]*inv;
  o[13] = h_c - h_sd; o[14] = h_c + h_sd; o[15] = w_c - w_sd; o[16] = w_c + w_sd;
}

extern "C" void kernel_launch(void* const* d_in, const int* in_sizes, int n_in,
                              void* d_out, int out_size, void* d_ws, size_t ws_size,
                              hipStream_t stream) {
  const int*   X  = (const int*)d_in[0];
  const float* w1 = (const float*)d_in[1];
  const float* b1 = (const float*)d_in[2];
  const float* w2 = (const float*)d_in[3];
  const float* b2 = (const float*)d_in[4];
  const float* w3 = (const float*)d_in[5];
  const float* b3 = (const float*)d_in[6];

  float* out   = (float*)d_out;
  float* A_out = out;                           // (B,H,W,K) f32
  float* T_out = out + (size_t)NPIX * KK;       // (B,K,17)

  char*  ws   = (char*)d_ws;
  f16*   bufA = (f16*)ws;                                   // 32 MB planes (ping); part aliases later
  f16*   bufB = (f16*)(ws + (size_t)32*1024*1024);          // 32 MB planes (pong); phi first
  float* wb   = (float*)(ws + (size_t)64*1024*1024);        // 8 MB (pre-scaled w')
  float* part = (float*)ws;                                 // aliases bufA (dead at pool time)

  f16* phi = bufB;   // [px][32] layout, consumed by aff only
  cnn_kernel<<<dim3(WD/32, HD/16, BB), 512, 0, stream>>>(X, w1, b1, w2, b2, w3, b3, phi);
  aff_kernel<<<1024, 256, 0, stream>>>(phi, wb);

  mp2_kernel<1><<<2048, 256, 0, stream>>>(nullptr, wb, bufA);  // iters 1,2 (analytic A0)
  mp2_kernel<0><<<2048, 256, 0, stream>>>(bufA, wb, bufB);     // iters 3,4
  mp2_kernel<0><<<2048, 256, 0, stream>>>(bufB, wb, bufA);     // iters 5,6
  mp2_kernel<0><<<2048, 256, 0, stream>>>(bufA, wb, bufB);     // iters 7,8 -> planes in bufB

  conv_kernel<<<NPIX*4/256, 256, 0, stream>>>(bufB, A_out);
  pool1_kernel<<<dim3(BB, 32), 256, 0, stream>>>(bufB, X, part);
  pool2_kernel<<<(BB*KK + 255)/256, 256, 0, stream>>>(part, T_out);
}

// Round 9
// 236.162 us; speedup vs baseline: 1.3020x; 1.1424x over previous
//
#include <hip/hip_runtime.h>
#include <math.h>

#define HD 128
#define WD 128
#define BB 32
#define KK 32
#define NPIX (BB*HD*WD)   // 524288
#define PLANE ((size_t)NPIX*8)   // f16 elems per plane

typedef _Float16 f16;
typedef __attribute__((ext_vector_type(8))) _Float16 f16x8;
typedef __attribute__((ext_vector_type(4))) _Float16 f16x4;
typedef __attribute__((ext_vector_type(4))) float f32x4;

// byte offset of 16B chunk g within 64B row; bijective over (row mod 8) -> all 32 banks
__device__ __forceinline__ int swz(int row, int g){
  return row*64 + (((g + (row >> 1)) & 3) << 4);
}

__device__ __forceinline__ float xexp2(float x){
#if __has_builtin(__builtin_amdgcn_exp2f)
  return __builtin_amdgcn_exp2f(x);
#else
  return exp2f(x);
#endif
}
__device__ __forceinline__ float xrcp(float x){
#if __has_builtin(__builtin_amdgcn_rcpf)
  return __builtin_amdgcn_rcpf(x);
#else
  return 1.f/x;
#endif
}
__device__ __forceinline__ f16x8 bc8(f16 x){
  f16x8 v;
  #pragma unroll
  for (int j = 0; j < 8; j++) v[j] = x;
  return v;
}

#define WSCALE 2.8853900817779268f   // 2*log2(e)

// ---------------- fused CNN + affinity: one-hot->conv1->conv2->conv3(phi in LDS)->aff->wb ----------------
// tile 16x32 interior; x1 on 20x36 (720), phi on 18x34 (612, padded to 640 for MFMA); 512 threads
__global__ __launch_bounds__(512, 4) void cnnaff_kernel(
    const int* __restrict__ X,
    const float* __restrict__ w1, const float* __restrict__ b1,
    const float* __restrict__ w2, const float* __restrict__ b2,
    const float* __restrict__ w3, const float* __restrict__ b3,
    float* __restrict__ wb)
{
  __shared__ f16 sW1f[9*11*40];      // 7920 B  [tap][class(11;10=zero)][40-pad oc], bias in tap4
  __shared__ int   sX[22*38];        // 3344 B
  __shared__ float sB2[32], sB3[32];
  __shared__ f16 x1[720*32];         // 46080 B: x1 (20x36) -> y2 (18x34 lin) -> phi (in-place)
  __shared__ f16 w2t[9*32*32];       // 18432 B [tap*32+oc][ic], swizzled
  __shared__ f16 w3t[32*32];         // 2048 B  [oe][ic], swizzled

  const int tid = threadIdx.x;
  const int img = blockIdx.z;
  const int bh0 = blockIdx.y * 16;
  const int bw0 = blockIdx.x * 32;

  for (int i = tid; i < 9*11*32; i += 512) {
    int tap = i / 352, c = (i % 352) >> 5, oc = i & 31;
    float v = (c < 10) ? w1[tap*320 + c*32 + oc] : 0.f;
    if (tap == 4 && c < 10) v += b1[oc];
    sW1f[(tap*11 + c)*40 + oc] = (f16)v;
  }
  for (int i = tid; i < 9*32*32; i += 512) {
    int tap = i >> 10, ic = (i >> 5) & 31, oc = i & 31;
    int off = swz(tap*32 + oc, ic >> 3) + (ic & 7)*2;
    *(f16*)((char*)w2t + off) = (f16)w2[i];
  }
  for (int i = tid; i < 32*32; i += 512) {
    int ic = i >> 5, oe = i & 31;
    int off = swz(oe, ic >> 3) + (ic & 7)*2;
    *(f16*)((char*)w3t + off) = (f16)w3[i];
  }
  if (tid < 32) { sB2[tid] = b2[tid]; sB3[tid] = b3[tid]; }
  for (int i = tid; i < 22*38; i += 512) {
    int ti = i / 38, tj = i % 38;
    int gh = bh0 - 3 + ti, gw = bw0 - 3 + tj;
    sX[i] = (gh >= 0 && gh < HD && gw >= 0 && gw < WD) ? X[(img*HD + gh)*WD + gw] : 10;
  }
  __syncthreads();

  // conv1 on 20x36 (x1 origin (-2,-2); sX origin (-3,-3))
  for (int p = tid; p < 720; p += 512) {
    int r = p / 36, c = p - r*36;
    int gh = bh0 - 2 + r, gw = bw0 - 2 + c;
    if (gh >= 0 && gh < HD && gw >= 0 && gw < WD) {
      f16x8 acc[4];
      {
        int cc = sX[r*38 + c];
        const f16* wr = &sW1f[cc*40];
        #pragma unroll
        for (int g = 0; g < 4; g++) acc[g] = *(const f16x8*)(wr + g*8);
      }
      #pragma unroll
      for (int tap = 1; tap < 9; tap++) {
        const int ti = tap/3, tj = tap%3;
        int cc = sX[(r+ti)*38 + c + tj];
        const f16* wr = &sW1f[(tap*11 + cc)*40];
        #pragma unroll
        for (int g = 0; g < 4; g++) acc[g] += *(const f16x8*)(wr + g*8);
      }
      #pragma unroll
      for (int g = 0; g < 4; g++) {
        f16x8 rr = acc[g];
        #pragma unroll
        for (int j = 0; j < 8; j++) rr[j] = (rr[j] > (f16)0.f) ? rr[j] : (f16)0.f;
        *(f16x8*)((char*)x1 + swz(p, g)) = rr;
      }
    } else {
      f16x8 z;
      #pragma unroll
      for (int j = 0; j < 8; j++) z[j] = (f16)0.f;
      #pragma unroll
      for (int g = 0; g < 4; g++) *(f16x8*)((char*)x1 + swz(p, g)) = z;
    }
  }
  __syncthreads();

  // conv2 via MFMA on 640 px (612 valid, linear 18x34 index)
  const int lane = tid & 63;
  const int wv   = tid >> 6;
  const int lr   = lane & 15;
  const int kg   = lane >> 4;
  const int mts  = wv * 5;

  int arow0[5];
  #pragma unroll
  for (int q = 0; q < 5; q++) {
    int px = (mts + q)*16 + lr;
    int pr = px / 34, pc = px - pr*34;
    arow0[q] = pr*36 + pc;
  }
  float b2v0 = sB2[lr], b2v1 = sB2[lr + 16];
  f32x4 acc[5][2];
  #pragma unroll
  for (int q = 0; q < 5; q++) {
    acc[q][0] = (f32x4){b2v0, b2v0, b2v0, b2v0};
    acc[q][1] = (f32x4){b2v1, b2v1, b2v1, b2v1};
  }
  #pragma unroll
  for (int tap = 0; tap < 9; tap++) {
    const int ti = tap/3, tj = tap%3;
    f16x8 bf0 = *(const f16x8*)((const char*)w2t + swz(tap*32 + lr,      kg));
    f16x8 bf1 = *(const f16x8*)((const char*)w2t + swz(tap*32 + lr + 16, kg));
    #pragma unroll
    for (int q = 0; q < 5; q++) {
      int row = arow0[q] + ti*36 + tj;
      f16x8 af = *(const f16x8*)((const char*)x1 + swz(row, kg));
      acc[q][0] = __builtin_amdgcn_mfma_f32_16x16x32_f16(af, bf0, acc[q][0], 0, 0, 0);
      acc[q][1] = __builtin_amdgcn_mfma_f32_16x16x32_f16(af, bf1, acc[q][1], 0, 0, 0);
    }
  }
  __syncthreads();

  // relu -> y2 (reuse x1, linear 18x34 slots 0..639)
  #pragma unroll
  for (int q = 0; q < 5; q++)
    #pragma unroll
    for (int nt = 0; nt < 2; nt++) {
      int oc = nt*16 + lr;
      #pragma unroll
      for (int rg = 0; rg < 4; rg++) {
        int px = (mts + q)*16 + kg*4 + rg;
        int off = swz(px, oc >> 3) + (oc & 7)*2;
        *(f16*)((char*)x1 + off) = (f16)fmaxf(acc[q][nt][rg], 0.f);
      }
    }
  __syncthreads();

  // conv3 via MFMA, phi written in-place over y2 (per-px 1x1, disjoint per wave)
  {
    f16x8 cf0 = *(const f16x8*)((const char*)w3t + swz(lr,      kg));
    f16x8 cf1 = *(const f16x8*)((const char*)w3t + swz(lr + 16, kg));
    float b3v0 = sB3[lr], b3v1 = sB3[lr + 16];
    #pragma unroll
    for (int q = 0; q < 5; q++) {
      f16x8 af = *(const f16x8*)((const char*)x1 + swz((mts + q)*16 + lr, kg));
      f32x4 o0 = (f32x4){b3v0, b3v0, b3v0, b3v0};
      f32x4 o1 = (f32x4){b3v1, b3v1, b3v1, b3v1};
      o0 = __builtin_amdgcn_mfma_f32_16x16x32_f16(af, cf0, o0, 0, 0, 0);
      o1 = __builtin_amdgcn_mfma_f32_16x16x32_f16(af, cf1, o1, 0, 0, 0);
      #pragma unroll
      for (int rg = 0; rg < 4; rg++) {
        int px = (mts + q)*16 + kg*4 + rg;
        // write phi[px][lr] and phi[px][lr+16] via swizzled f16 slots
        int offA = swz(px, lr >> 3) + (lr & 7)*2;
        int offB = swz(px, (lr+16) >> 3) + (lr & 7)*2;
        *(f16*)((char*)x1 + offA) = (f16)o0[rg];
        *(f16*)((char*)x1 + offB) = (f16)o1[rg];
      }
    }
  }
  __syncthreads();

  // aff: interior 16x32, phi in LDS (18x34 linear)
  {
    int r2 = tid >> 5, c2 = tid & 31;
    int gh = bh0 + r2, gw = bw0 + c2;
    int qc = (r2+1)*34 + (c2+1);
    f16x8 c0 = *(const f16x8*)((const char*)x1 + swz(qc, 0));
    f16x8 c1 = *(const f16x8*)((const char*)x1 + swz(qc, 1));
    f16x8 c2v = *(const f16x8*)((const char*)x1 + swz(qc, 2));
    f16x8 c3 = *(const f16x8*)((const char*)x1 + swz(qc, 3));
    float4 out;
    #pragma unroll
    for (int d = 0; d < 4; d++) {
      int slot = (d == 0) ? qc + 34 : (d == 1) ? qc - 34 : (d == 2) ? qc + 1 : qc - 1;
      bool valid = (d == 0) ? (gh < HD-1) : (d == 1) ? (gh > 0) : (d == 2) ? (gw < WD-1) : (gw > 0);
      f16x8 n0 = *(const f16x8*)((const char*)x1 + swz(slot, 0));
      f16x8 n1 = *(const f16x8*)((const char*)x1 + swz(slot, 1));
      f16x8 n2 = *(const f16x8*)((const char*)x1 + swz(slot, 2));
      f16x8 n3 = *(const f16x8*)((const char*)x1 + swz(slot, 3));
      f16x8 d0 = c0 - n0; f16x8 s = d0*d0;
      f16x8 d1 = c1 - n1; s += d1*d1;
      f16x8 d2 = c2v - n2; s += d2*d2;
      f16x8 d3 = c3 - n3; s += d3*d3;
      float d2f = 0.f;
      #pragma unroll
      for (int j = 0; j < 8; j++) d2f += (float)s[j];
      float v = valid ? WSCALE * xexp2(-WSCALE * d2f) : 0.f;
      if (d == 0) out.x = v; else if (d == 1) out.y = v; else if (d == 2) out.z = v; else out.w = v;
    }
    ((float4*)wb)[(size_t)img*HD*WD + gh*WD + gw] = out;
  }
}

// ---------------- analytic A0 accumulate (separable) ----------------
__device__ __forceinline__ void a0_accum2(float* a, int hh, int ww, float wt) {
  const float C = 0.0028177637517362567f;  // log2(e)/512
  float eh[4], ew[8];
  float sh = 0.f, sw = 0.f;
  const float fh = (float)hh, fw = (float)ww;
  #pragma unroll
  for (int kh = 0; kh < 4; kh++) { float d = fh - (float)(kh*32+16); eh[kh] = xexp2(-d*d*C); sh += eh[kh]; }
  #pragma unroll
  for (int kw = 0; kw < 8; kw++) { float d = fw - (float)(kw*16+8); ew[kw] = xexp2(-d*d*C); sw += ew[kw]; }
  float sc = wt * xrcp(sh * sw);
  #pragma unroll
  for (int kh = 0; kh < 4; kh++) {
    float ehs = eh[kh] * sc;
    #pragma unroll
    for (int kw = 0; kw < 8; kw++) a[kh*8+kw] = fmaf(ehs, ew[kw], a[kh*8+kw]);
  }
}

// ---------------- fused message-pass pair; plane-major A[g][px][8]; 512 thr, tile 16x32 ----------------
// LAST=1: writes canonical f32 A via LDS transpose (coalesced), no planes output
template<int FIRST, int LAST>
__global__ __launch_bounds__(512, 6) void mp2_kernel(const f16* __restrict__ Ain,
                                                     const float* __restrict__ wb,
                                                     f16* __restrict__ Aout,
                                                     float* __restrict__ AoutF) {
  __shared__ f16 amid[612*32];   // 18x34 px, swizzled; reused as planes buffer in LAST

  const int blk  = blockIdx.x;          // 1024
  const int xcd  = blk & 7;
  const int q    = blk >> 3;            // 0..127
  const int img  = xcd + ((q >> 5) << 3);
  const int tile = q & 31;
  const int th0  = (tile >> 2) * 16;
  const int tw0  = (tile & 3) * 32;
  const size_t ibase = (size_t)img * HD * WD;

  // ---- phase A: amid 18x34 (1-px halo), neighbors from plane-major global ----
  for (int p = threadIdx.x; p < 612; p += 512) {
    int r = p / 34, cc = p - r*34;
    int gh = th0 - 1 + r, gw = tw0 - 1 + cc;
    bool inimg = ((unsigned)gh < (unsigned)HD) && ((unsigned)gw < (unsigned)WD);
    int ghc = min(max(gh, 0), HD-1), gwc = min(max(gw, 0), WD-1);
    float4 wd = inimg ? ((const float4*)wb)[ibase + gh*WD + gw] : make_float4(0.f,0.f,0.f,0.f);
    int hu = ghc + ((ghc < HD-1) ? 1 : 0);
    int hd = ghc - ((ghc > 0)    ? 1 : 0);
    int wl = gwc + ((gwc < WD-1) ? 1 : 0);
    int wr = gwc - ((gwc > 0)    ? 1 : 0);

    float s = 0.f;
    f16x8 pe[4];
    if (FIRST) {
      float a[32];
      #pragma unroll
      for (int k = 0; k < 32; k++) a[k] = 0.f;
      a0_accum2(a, hu, gwc, wd.x);
      a0_accum2(a, hd, gwc, wd.y);
      a0_accum2(a, ghc, wl, wd.z);
      a0_accum2(a, ghc, wr, wd.w);
      #pragma unroll
      for (int g = 0; g < 4; g++)
        #pragma unroll
        for (int j = 0; j < 8; j++) { float e = xexp2(a[g*8+j]); s += e; pe[g][j] = (f16)e; }
    } else {
      const size_t iu_ = ibase + (size_t)hu*WD + gwc;
      const size_t id_ = ibase + (size_t)hd*WD + gwc;
      const size_t il_ = ibase + (size_t)ghc*WD + wl;
      const size_t ir_ = ibase + (size_t)ghc*WD + wr;
      f16x8 w0 = bc8((f16)wd.x), w1 = bc8((f16)wd.y), w2 = bc8((f16)wd.z), w3 = bc8((f16)wd.w);
      #pragma unroll
      for (int g = 0; g < 4; g++) {
        const f16* pg = Ain + (size_t)g*PLANE;
        f16x8 v0 = *(const f16x8*)(pg + iu_*8);
        f16x8 v1 = *(const f16x8*)(pg + id_*8);
        f16x8 v2 = *(const f16x8*)(pg + il_*8);
        f16x8 v3 = *(const f16x8*)(pg + ir_*8);
        f16x8 agg = v0*w0 + v1*w1 + v2*w2 + v3*w3;
        #pragma unroll
        for (int j = 0; j < 8; j++) { float e = xexp2((float)agg[j]); s += e; pe[g][j] = (f16)e; }
      }
    }
    f16x8 iv = bc8((f16)xrcp(s));
    #pragma unroll
    for (int g = 0; g < 4; g++)
      *(f16x8*)((char*)amid + swz(p, g)) = pe[g]*iv;
  }
  __syncthreads();

  // ---- phase B: interior 16x32, 1 px/thread ----
  {
    int r2 = threadIdx.x >> 5, c2 = threadIdx.x & 31;
    int gh = th0 + r2, gw = tw0 + c2;
    int rm = r2 + 1, cm = c2 + 1;
    float4 wd = ((const float4*)wb)[ibase + gh*WD + gw];
    int q0 = (rm + ((gh < HD-1) ? 1 : 0))*34 + cm;
    int q1 = (rm - ((gh > 0)    ? 1 : 0))*34 + cm;
    int q2 = rm*34 + cm + ((gw < WD-1) ? 1 : 0);
    int q3 = rm*34 + cm - ((gw > 0)    ? 1 : 0);
    f16x8 w0 = bc8((f16)wd.x), w1 = bc8((f16)wd.y), w2 = bc8((f16)wd.z), w3 = bc8((f16)wd.w);
    float s = 0.f;
    f16x8 pe[4];
    #pragma unroll
    for (int g = 0; g < 4; g++) {
      f16x8 v0 = *(const f16x8*)((const char*)amid + swz(q0, g));
      f16x8 v1 = *(const f16x8*)((const char*)amid + swz(q1, g));
      f16x8 v2 = *(const f16x8*)((const char*)amid + swz(q2, g));
      f16x8 v3 = *(const f16x8*)((const char*)amid + swz(q3, g));
      f16x8 agg = v0*w0 + v1*w1 + v2*w2 + v3*w3;
      #pragma unroll
      for (int j = 0; j < 8; j++) { float e = xexp2((float)agg[j]); s += e; pe[g][j] = (f16)e; }
    }
    f16x8 iv = bc8((f16)xrcp(s));
    #pragma unroll
    for (int g = 0; g < 4; g++) pe[g] = pe[g]*iv;

    if (!LAST) {
      size_t opix = ibase + (size_t)gh*WD + gw;
      #pragma unroll
      for (int g = 0; g < 4; g++)
        *(f16x8*)(Aout + (size_t)g*PLANE + opix*8) = pe[g];
    } else {
      // stash planes in LDS (g-stride 513 avoids read-bank clash), then coalesced f32 out
      __syncthreads();                       // amid reads complete
      f16* planes = amid;
      #pragma unroll
      for (int g = 0; g < 4; g++)
        *(f16x8*)((char*)planes + (g*513 + threadIdx.x)*16) = pe[g];
      __syncthreads();
      float* obase = AoutF + ((size_t)(img*HD + th0)*WD + tw0)*32;
      #pragma unroll
      for (int rep = 0; rep < 8; rep++) {
        int flat = rep*512 + threadIdx.x;     // 0..4095 chunks of 16B
        int row = flat >> 8;                  // 0..15
        int within = flat & 255;
        int pxr = within >> 3;                // 0..31
        int kq = within & 7;                  // 0..7
        int g = kq >> 1, half = kq & 1;
        int pxl = row*32 + pxr;
        f16x4 v = *(const f16x4*)((const char*)planes + (g*513 + pxl)*16 + half*8);
        float4 o;
        o.x = (float)v[0]; o.y = (float)v[1]; o.z = (float)v[2]; o.w = (float)v[3];
        *(float4*)(obase + (size_t)row*WD*32 + pxr*32 + kq*4) = o;
      }
    }
  }
}

// ---------------- pooled features, stage 1 (reads canonical f32 A) ----------------
__global__ __launch_bounds__(256) void pool1_kernel(const float* __restrict__ A,
                                                    const int* __restrict__ X,
                                                    float* __restrict__ part) {
  const int b = blockIdx.x, cy = blockIdx.y;
  const int k = threadIdx.x & 31, sub = threadIdx.x >> 5;
  const int h = cy*4 + (sub >> 1);
  const int w0 = (sub & 1) * 64;
  const float hh = ((float)h + 0.5f) * (1.f/128.f);
  float s0 = 0.f, sw = 0.f, sw2 = 0.f;
  float col[10];
  #pragma unroll
  for (int c = 0; c < 10; c++) col[c] = 0.f;
  const float* Arow = A + ((size_t)((b*HD + h)*WD + w0))*32 + k;
  const int*   Xrow = X + (b*HD + h)*WD + w0;
  for (int w = 0; w < 64; w++) {
    float a  = Arow[(size_t)w*32];
    float ww = ((float)(w + w0) + 0.5f) * (1.f/128.f);
    s0 += a; sw = fmaf(ww, a, sw); sw2 = fmaf(ww*ww, a, sw2);
    int x = Xrow[w];
    #pragma unroll
    for (int c = 0; c < 10; c++) col[c] += (x == c) ? a : 0.f;
  }
  __shared__ float red[8][32][15];
  float vals[15];
  vals[0] = s0; vals[1] = hh*s0; vals[2] = sw; vals[3] = hh*hh*s0; vals[4] = sw2;
  #pragma unroll
  for (int c = 0; c < 10; c++) vals[5+c] = col[c];
  #pragma unroll
  for (int q = 0; q < 15; q++) red[sub][k][q] = vals[q];
  __syncthreads();
  if (sub == 0) {
    #pragma unroll
    for (int q = 0; q < 15; q++) {
      float v = 0.f;
      #pragma unroll
      for (int s2 = 0; s2 < 8; s2++) v += red[s2][k][q];
      part[(((size_t)b*32 + cy)*32 + k)*15 + q] = v;
    }
  }
}

// ---------------- pooled features, stage 2 ----------------
__global__ __launch_bounds__(256) void pool2_kernel(const float* __restrict__ part,
                                                    float* __restrict__ T) {
  const int t = blockIdx.x * 256 + threadIdx.x;
  if (t >= BB*KK) return;
  const int b = t >> 5, k = t & 31;
  float s[15];
  #pragma unroll
  for (int q = 0; q < 15; q++) s[q] = 0.f;
  for (int cy = 0; cy < 32; cy++) {
    const float* p = part + (((size_t)b*32 + cy)*32 + k)*15;
    #pragma unroll
    for (int q = 0; q < 15; q++) s[q] += p[q];
  }
  float mass = s[0] + 1e-6f;
  float inv  = 1.f / mass;
  float h_c = s[1]*inv, w_c = s[2]*inv, h2 = s[3]*inv, w2 = s[4]*inv;
  float h_sd = sqrtf(fmaxf(h2 - h_c*h_c, 0.f) + 1e-6f);
  float w_sd = sqrtf(fmaxf(w2 - w_c*w_c, 0.f) + 1e-6f);
  float* o = T + (size_t)t*17;
  o[0] = mass * (1.f/16384.f);
  o[1] = h_c; o[2] = w_c;
  #pragma unroll
  for (int c = 0; c < 10; c++) o[3+c] = s[5+c]*inv;
  o[13] = h_c - h_sd; o[14] = h_c + h_sd; o[15] = w_c - w_sd; o[16] = w_c + w_sd;
}

extern "C" void kernel_launch(void* const* d_in, const int* in_sizes, int n_in,
                              void* d_out, int out_size, void* d_ws, size_t ws_size,
                              hipStream_t stream) {
  const int*   X  = (const int*)d_in[0];
  const float* w1 = (const float*)d_in[1];
  const float* b1 = (const float*)d_in[2];
  const float* w2 = (const float*)d_in[3];
  const float* b2 = (const float*)d_in[4];
  const float* w3 = (const float*)d_in[5];
  const float* b3 = (const float*)d_in[6];

  float* out   = (float*)d_out;
  float* A_out = out;                           // (B,H,W,K) f32
  float* T_out = out + (size_t)NPIX * KK;       // (B,K,17)

  char*  ws   = (char*)d_ws;
  f16*   bufA = (f16*)ws;                                   // 32 MB planes (ping)
  f16*   bufB = (f16*)(ws + (size_t)32*1024*1024);          // 32 MB planes (pong)
  float* wb   = (float*)(ws + (size_t)64*1024*1024);        // 8 MB (pre-scaled w')
  float* part = (float*)ws;                                 // aliases bufA (dead at pool time)

  cnnaff_kernel<<<dim3(WD/32, HD/16, BB), 512, 0, stream>>>(X, w1, b1, w2, b2, w3, b3, wb);

  mp2_kernel<1,0><<<1024, 512, 0, stream>>>(nullptr, wb, bufA, nullptr);  // iters 1,2 (analytic A0)
  mp2_kernel<0,0><<<1024, 512, 0, stream>>>(bufA, wb, bufB, nullptr);     // iters 3,4
  mp2_kernel<0,0><<<1024, 512, 0, stream>>>(bufB, wb, bufA, nullptr);     // iters 5,6
  mp2_kernel<0,1><<<1024, 512, 0, stream>>>(bufA, wb, nullptr, A_out);    // iters 7,8 -> f32 canonical

  pool1_kernel<<<dim3(BB, 32), 256, 0, stream>>>(A_out, X, part);
  pool2_kernel<<<(BB*KK + 255)/256, 256, 0, stream>>>(part, T_out);
}